// Round 7
// baseline (704.894 us; speedup 1.0000x reference)
//
#include <hip/hip_runtime.h>

#define D_MODEL 2048
#define S_LEN 2048
#define NB 2
#define NH 16
#define DK 128

typedef __attribute__((ext_vector_type(8))) __bf16 bf16x8;
typedef __attribute__((ext_vector_type(4))) float f32x4;

__device__ __forceinline__ unsigned short f2bf(float f) {
    union { __bf16 b; unsigned short u; } cv;
    cv.b = (__bf16)f;   // hardware v_cvt, RNE
    return cv.u;
}

__device__ __forceinline__ void gld_lds16(const void* g, void* l) {
    __builtin_amdgcn_global_load_lds(
        (const __attribute__((address_space(1))) unsigned int*)g,
        (__attribute__((address_space(3))) unsigned int*)l, 16, 0, 0);
}

// ---- fused cast: inp (2 slices) + 4 weights, all slices n4 float4s ---------
__global__ void cast_all(const float* __restrict__ inp,
                         const float* __restrict__ wq, const float* __restrict__ wk,
                         const float* __restrict__ wv, const float* __restrict__ wo,
                         unsigned short* inp_b, unsigned short* wq_b,
                         unsigned short* wk_b, unsigned short* wv_b,
                         unsigned short* wo_b, int n4) {
    const int s = blockIdx.y;  // 0,1: inp halves; 2..5: weights
    const float4* x4;
    ushort4* y4;
    if (s == 0)      { x4 = (const float4*)inp;            y4 = (ushort4*)inp_b; }
    else if (s == 1) { x4 = (const float4*)inp + n4;       y4 = (ushort4*)inp_b + n4; }
    else if (s == 2) { x4 = (const float4*)wq;             y4 = (ushort4*)wq_b; }
    else if (s == 3) { x4 = (const float4*)wk;             y4 = (ushort4*)wk_b; }
    else if (s == 4) { x4 = (const float4*)wv;             y4 = (ushort4*)wv_b; }
    else             { x4 = (const float4*)wo;             y4 = (ushort4*)wo_b; }
    int i = blockIdx.x * blockDim.x + threadIdx.x;
    int stride = gridDim.x * blockDim.x;
    for (; i < n4; i += stride) {
        float4 v = x4[i];
        ushort4 o;
        o.x = f2bf(v.x); o.y = f2bf(v.y); o.z = f2bf(v.z); o.w = f2bf(v.w);
        y4[i] = o;
    }
}

// -------- GEMM (m97 + XOR-swizzled LDS): C[m,n] = sum_k A[m,k]*Bt[n,k] ------
#define BM 128
#define BN 128
#define BK 64

__device__ __forceinline__ void cstore(float* p, float v) { *p = v; }
__device__ __forceinline__ void cstore(unsigned short* p, float v) { *p = f2bf(v); }

template <typename OutT>
__device__ __forceinline__ void gemm_body(const unsigned short* __restrict__ A,
                                          const unsigned short* __restrict__ Bt,
                                          OutT* __restrict__ C,
                                          int N, int K, int m0, int n0) {
    __shared__ __align__(16) unsigned short As[BM * BK];
    __shared__ __align__(16) unsigned short Bs[BN * BK];
    const int tid = threadIdx.x;
    const int lane = tid & 63;
    const int wave = tid >> 6;
    const int quad = lane >> 4;
    const int l15 = lane & 15;
    const int wr = (wave >> 1) * 64;
    const int wc = (wave & 1) * 64;

    const int slotbase = wave * 64 + lane;

    f32x4 zero = {0.f, 0.f, 0.f, 0.f};
    f32x4 acc[4][4];
    for (int i = 0; i < 4; i++)
        for (int j = 0; j < 4; j++) acc[i][j] = zero;

    for (int k0 = 0; k0 < K; k0 += BK) {
        __syncthreads();
#pragma unroll
        for (int t = 0; t < 4; t++) {
            int slot = t * 256 + slotbase;
            int row = slot >> 3;
            int cg = (slot & 7) ^ (row & 7);
            gld_lds16(A + (size_t)(m0 + row) * K + k0 + cg * 8, &As[slot * 8]);
            gld_lds16(Bt + (size_t)(n0 + row) * K + k0 + cg * 8, &Bs[slot * 8]);
        }
        __syncthreads();

        bf16x8 af[4][2], bfr[4][2];
#pragma unroll
        for (int t = 0; t < 4; t++)
#pragma unroll
            for (int c = 0; c < 2; c++) {
                int ch = (c * 4 + quad) ^ (l15 & 7);
                af[t][c]  = *(const bf16x8*)(&As[((wr + t * 16 + l15) * 8 + ch) * 8]);
                bfr[t][c] = *(const bf16x8*)(&Bs[((wc + t * 16 + l15) * 8 + ch) * 8]);
            }
#pragma unroll
        for (int c = 0; c < 2; c++)
#pragma unroll
            for (int mt = 0; mt < 4; mt++)
#pragma unroll
                for (int nt = 0; nt < 4; nt++)
                    acc[mt][nt] = __builtin_amdgcn_mfma_f32_16x16x32_bf16(
                        af[mt][c], bfr[nt][c], acc[mt][nt], 0, 0, 0);
    }

#pragma unroll
    for (int mt = 0; mt < 4; mt++)
#pragma unroll
        for (int nt = 0; nt < 4; nt++)
#pragma unroll
            for (int r = 0; r < 4; r++) {
                int m = m0 + wr + mt * 16 + quad * 4 + r;
                int n = n0 + wc + nt * 16 + l15;
                cstore(&C[(size_t)m * N + n], acc[mt][nt][r]);
            }
}

// all three projections in one launch: 1536 blocks
__global__ __launch_bounds__(256) void gemm_qkv(
        const unsigned short* __restrict__ inp,
        const unsigned short* __restrict__ wq,
        const unsigned short* __restrict__ wk,
        const unsigned short* __restrict__ wv,
        unsigned short* __restrict__ Qo,
        unsigned short* __restrict__ Ko,
        unsigned short* __restrict__ Vto) {
    const int bid = blockIdx.x;
    const unsigned short *A, *Bt;
    unsigned short* C;
    int N, m0, n0;
    if (bid < 1024) {                  // Q (0..511) and K (512..1023)
        int sel = bid >> 9;
        int r = bid & 511;
        A = inp; Bt = sel ? wk : wq; C = sel ? Ko : Qo;
        N = D_MODEL;
        m0 = (r & 31) * BM;            // 32 m-tiles over 4096
        n0 = (r >> 5) * BN;            // 16 n-tiles over 2048
    } else {                           // V^T = Wv * X^T (512 blocks)
        int r = bid - 1024;
        A = wv; Bt = inp; C = Vto;
        N = NB * S_LEN;
        m0 = (r & 15) * BM;            // 16 m-tiles over 2048
        n0 = (r >> 4) * BN;            // 32 n-tiles over 4096
    }
    gemm_body(A, Bt, C, N, D_MODEL, m0, n0);
}

__global__ __launch_bounds__(256) void gemm_out(const unsigned short* __restrict__ A,
                                                const unsigned short* __restrict__ Bt,
                                                float* __restrict__ C) {
    gemm_body(A, Bt, C, D_MODEL, D_MODEL, blockIdx.x * BM, blockIdx.y * BN);
}

// ---- Flash attention: 512 thr, QT=128, 3 blocks/CU, K-prefetch -------------
#define QT 128
#define PS_STRIDE 72  // 64 + 8 pad
#define NT (S_LEN / 64)

__global__ __launch_bounds__(512, 6) void flash_attn(
        const unsigned short* __restrict__ Q,
        const unsigned short* __restrict__ K,
        const unsigned short* __restrict__ Vt,   // [D_MODEL][NB*S_LEN]  (= V^T)
        const float* __restrict__ bias,
        const int* __restrict__ softcap,
        unsigned short* __restrict__ O) {
    // K tile [64 r][16 ch], chunk c at c^(r&15); V^T tile [128 r][8 ch], c^(r&7)
    __shared__ __align__(16) unsigned short Ks[64 * DK];       // 16 KB
    __shared__ __align__(16) unsigned short Vts[DK * 64];      // 16 KB (single)
    __shared__ __align__(16) unsigned short Ps[8 * 16 * PS_STRIDE];  // 18 KB

    const int tid = threadIdx.x;
    const int lane = tid & 63;
    const int wave = tid >> 6;          // 0..7
    const int quad = lane >> 4;
    const int l15 = lane & 15;
    const int q0 = blockIdx.x * QT;
    const int h = blockIdx.y;
    const int b = blockIdx.z;

    const float scale = 0.08838834764831845f;  // 1/sqrt(128)
    const float cap = (float)softcap[0];
    const float LOG2E = 1.4426950408889634f;
    const float c1 = 2.0f * LOG2E * scale / cap;
    const float c2 = 2.0f * LOG2E / cap;
    const float c3 = -2.0f * cap * LOG2E;

    const size_t head_off = (size_t)b * S_LEN * D_MODEL + (size_t)h * DK;
    const size_t vt_row = (size_t)NB * S_LEN;
    const unsigned short* Vh = Vt + (size_t)h * DK * vt_row + (size_t)b * S_LEN;

    // Q fragments (A-layout): 16 q-rows per wave
    bf16x8 qf[4];
    {
        const unsigned short* Qp = Q + head_off + (size_t)(q0 + wave * 16 + l15) * D_MODEL;
#pragma unroll
        for (int c = 0; c < 4; c++)
            qf[c] = *(const bf16x8*)(Qp + c * 32 + quad * 8);
    }

    f32x4 zero = {0.f, 0.f, 0.f, 0.f};
    float l_part[4] = {0.f, 0.f, 0.f, 0.f};
    f32x4 o_acc[8];
#pragma unroll
    for (int d = 0; d < 8; d++) o_acc[d] = zero;

    unsigned short* Psw = &Ps[wave * 16 * PS_STRIDE];
    const int qrow = q0 + wave * 16 + quad * 4;

    auto stageK = [&](int kbase) {
#pragma unroll
        for (int t = 0; t < 2; t++) {
            int slot = t * 512 + tid;               // 0..1023
            int kr = slot >> 4;
            int kc = (slot & 15) ^ (kr & 15);
            gld_lds16(K + head_off + (size_t)(kbase + kr) * D_MODEL + kc * 8,
                      &Ks[slot * 8]);
        }
    };
    auto stageV = [&](int kbase) {
#pragma unroll
        for (int t = 0; t < 2; t++) {
            int slot = t * 512 + tid;
            int vr = slot >> 3;
            int vc = (slot & 7) ^ (vr & 7);
            gld_lds16(Vh + (size_t)vr * vt_row + kbase + vc * 8,
                      &Vts[slot * 8]);
        }
    };

    stageK(0);
    stageV(0);

    for (int kt = 0; kt < NT; kt++) {
        const int kbase = kt * 64;
        __syncthreads();   // A: drain DMA -> Ks=K(kt), Vts=V(kt) ready

        // ---- S = Q K^T (16 q-rows x 64 keys per wave) ---------------------
        f32x4 s[4];
#pragma unroll
        for (int nt = 0; nt < 4; nt++) s[nt] = zero;
#pragma unroll
        for (int c = 0; c < 4; c++) {
            bf16x8 kf[4];
#pragma unroll
            for (int nt = 0; nt < 4; nt++)
                kf[nt] = *(const bf16x8*)(&Ks[((nt * 16 + l15) * 16 +
                                               ((c * 4 + quad) ^ l15)) * 8]);
#pragma unroll
            for (int nt = 0; nt < 4; nt++)
                s[nt] = __builtin_amdgcn_mfma_f32_16x16x32_bf16(qf[c], kf[nt], s[nt], 0, 0, 0);
        }

        __syncthreads();   // B: Ks free for restaging

        // bias prefetch BEFORE the DMA issue (in-order vmcnt retirement)
        float bb[4][4];
#pragma unroll
        for (int nt = 0; nt < 4; nt++) {
            const float* bp = bias + (size_t)qrow * S_LEN + kbase + nt * 16 + l15;
#pragma unroll
            for (int r = 0; r < 4; r++)
                bb[nt][r] = bp[(size_t)r * S_LEN];
        }
        __builtin_amdgcn_sched_barrier(0);

        if (kt + 1 < NT) stageK(kbase + 64);   // overlaps softmax+P+PV

        // ---- fused softcap+softmax (static max = cap) ---------------------
#pragma unroll
        for (int nt = 0; nt < 4; nt++) {
#pragma unroll
            for (int r = 0; r < 4; r++) {
                float arg = fmaf(s[nt][r], c1, bb[nt][r] * c2);
                float u = __builtin_amdgcn_exp2f(arg);
                float p = __builtin_amdgcn_exp2f(c3 * __builtin_amdgcn_rcpf(u + 1.0f));
                s[nt][r] = p;
                l_part[r] += p;
            }
        }

        // ---- P: C-layout -> per-wave LDS -> A-layout (no barrier) ---------
#pragma unroll
        for (int nt = 0; nt < 4; nt++)
#pragma unroll
            for (int r = 0; r < 4; r++)
                Psw[(quad * 4 + r) * PS_STRIDE + nt * 16 + l15] = f2bf(s[nt][r]);

        // ---- O += P V -----------------------------------------------------
#pragma unroll
        for (int c = 0; c < 2; c++) {
            bf16x8 pf = *(const bf16x8*)(&Psw[l15 * PS_STRIDE + c * 32 + quad * 8]);
#pragma unroll
            for (int dt = 0; dt < 8; dt++) {
                bf16x8 vf = *(const bf16x8*)(&Vts[((dt * 16 + l15) * 8 +
                                                   ((c * 4 + quad) ^ (l15 & 7))) * 8]);
                o_acc[dt] = __builtin_amdgcn_mfma_f32_16x16x32_bf16(pf, vf, o_acc[dt], 0, 0, 0);
            }
        }

        if (kt + 1 < NT) {
            __syncthreads();               // C: Vts free (PV done block-wide)
            stageV(kbase + 64);            // drains at next A
        }
    }

    // ---- finalize ---------------------------------------------------------
#pragma unroll
    for (int r = 0; r < 4; r++) {
        float l = l_part[r];
        l += __shfl_xor(l, 1, 64);
        l += __shfl_xor(l, 2, 64);
        l += __shfl_xor(l, 4, 64);
        l += __shfl_xor(l, 8, 64);
        float inv = 1.0f / l;
        int row = qrow + r;
        unsigned short* Op = O + (size_t)(b * S_LEN + row) * D_MODEL + h * DK;
#pragma unroll
        for (int dt = 0; dt < 8; dt++)
            Op[dt * 16 + l15] = f2bf(o_acc[dt][r] * inv);
    }
}

// ---------------- host ----------------
extern "C" void kernel_launch(void* const* d_in, const int* in_sizes, int n_in,
                              void* d_out, int out_size, void* d_ws, size_t ws_size,
                              hipStream_t stream) {
    const float* inp = (const float*)d_in[0];
    const float* wq  = (const float*)d_in[1];
    const float* wk  = (const float*)d_in[2];
    const float* wv  = (const float*)d_in[3];
    const float* wo  = (const float*)d_in[4];
    const float* bias = (const float*)d_in[5];
    const int* softcap = (const int*)d_in[6];
    float* out = (float*)d_out;

    unsigned short* ws = (unsigned short*)d_ws;
    const size_t n_inp = (size_t)NB * S_LEN * D_MODEL;
    const size_t n_w = (size_t)D_MODEL * D_MODEL;
    unsigned short* inp_b = ws;
    unsigned short* wq_b = inp_b + n_inp;
    unsigned short* wk_b = wq_b + n_w;
    unsigned short* wv_b = wk_b + n_w;
    unsigned short* wo_b = wv_b + n_w;
    unsigned short* Qb = wo_b + n_w;
    unsigned short* Kb = Qb + n_inp;
    unsigned short* Vtb = Kb + n_inp;   // [D_MODEL][NB*S_LEN] = V^T
    unsigned short* Ob = Vtb + n_inp;

    cast_all<<<dim3(256, 6), dim3(256), 0, stream>>>(
        inp, wq, wk, wv, wo, inp_b, wq_b, wk_b, wv_b, wo_b, (int)(n_w / 4));

    gemm_qkv<<<dim3(1536), 256, 0, stream>>>(inp_b, wq_b, wk_b, wv_b, Qb, Kb, Vtb);

    flash_attn<<<dim3(S_LEN / QT, NH, NB), 512, 0, stream>>>(Qb, Kb, Vtb, bias, softcap, Ob);

    gemm_out<<<dim3(NB * S_LEN / BM, D_MODEL / BN), 256, 0, stream>>>(Ob, wo_b, out);
}